// Round 25
// baseline (83.400 us; speedup 1.0000x reference)
//
#include <hip/hip_runtime.h>

// ChamferLoss: B=4, N=M=8192, D=3, fp32.
// loss = mean_b[ mean(pred2gt) + mean(gt2pred) + max(pred2gt) ]
// R33 = R32 (best measured, 75.2us: R19 base + async-stage split) + FUSED
//  finalization: reduce_all dispatch deleted; each nn block atomically folds
//  its (sum,max) partial into accum, counter-gated last block writes out[0].
//  Machinery verified in R29 (absmax 0). Zero-race argument: block(0,0,0)
//  zeroes accum in its FIRST instruction; consuming atomics execute only
//  after ~29us of per-block compute -> >=25us safety margin.
// Session model (R27 probe + 8 falsified mechanisms): nn ~29us = 6.6 MFMA +
//  ~9.4 VALU + ~13 barrier-phase stall (invariant to occupancy/shape/
//  pipelining/folds/AGPR/TLP/min3); async-split recovered ~1.1us of it.
//  Fixed ~40.2us harness ws-poison fill (84% HBM peak) dominates dur_us.
//   A row m (K=16): [xh0..2, xh0..2, xl0,xl1 | xl2, 1, 1, 0...]
//   B col n (K=16): [-2yh0..2, -2yl0..2, -2yh0,-2yh1 | -2yh2, y2h, y2l, 0...]
//   D = y2 - 2(xh.yh + xh.yl + xl.yh); d2 = x2 + min_y D  (xl.yl ~2^-18 dropped)

typedef short  s16x8  __attribute__((ext_vector_type(8)));
typedef float  f32x16 __attribute__((ext_vector_type(16)));

#define BATCH 4
#define NPTS  8192
#define TPB   512                  // 8 waves; 1 block/CU; 2 waves/SIMD
#define XPB   256                  // x per block: 8 waves x 1 tile x 32
#define NXC   (NPTS / XPB)         // 32
#define NPH   4                    // stage phases
#define PHPTS (NPTS / NPH)         // 2048 y-points per phase (64 KB LDS)
#define PHT   (PHPTS / 32)         // 64 y-tiles per phase
#define PPT   (PHPTS / TPB)        // 4 points per thread per phase
#define NBLK  (NXC * 2 * BATCH)    // 256 blocks total

__device__ __forceinline__ unsigned int bft(float f) { return __float_as_uint(f) >> 16; }
__device__ __forceinline__ float bfv(unsigned int s) { return __uint_as_float(s << 16); }

__global__ __launch_bounds__(TPB, 2)
void nn_fused(const float* __restrict__ pred, const float* __restrict__ gt,
              float* __restrict__ accum, float* __restrict__ out) {
    const int xc = blockIdx.x, bd = blockIdx.z;
    const int t = threadIdx.x;
    // Zero accum (8 f32 sums + 8 u32 maxbits + counter). Safe: consuming
    // atomics land only after each block's ~29us of compute.
    if (xc == 0 && bd == 0 && t < 17) ((unsigned int*)accum)[t] = 0u;

    const int b = bd >> 1, dir = bd & 1;
    const float* xp = (dir ? gt : pred) + (size_t)b * NPTS * 3;
    const float* yp = (dir ? pred : gt) + (size_t)b * NPTS * 3;

    const int wv = t >> 6, l = t & 63;
    const int m32 = l & 31, hh = l >> 5;

    // [tile(64)][{0..31: w0(k0-7), 32..63: w1(k8-15)}] per phase = 64 KB
    __shared__ uint4 ldsb[PHT * 64];

    // A-frag + x2 for the wave's single 32-row x-tile.
    const int xi = xc * XPB + wv * 32 + m32;
    const float c0 = xp[xi * 3], c1 = xp[xi * 3 + 1], c2 = xp[xi * 3 + 2];
    const float x2 = c0 * c0 + c1 * c1 + c2 * c2;
    s16x8 af;
    {
        const unsigned int xh0 = bft(c0), xh1 = bft(c1), xh2 = bft(c2);
        const unsigned int xl0 = bft(c0 - bfv(xh0));
        const unsigned int xl1 = bft(c1 - bfv(xh1));
        const unsigned int xl2 = bft(c2 - bfv(xh2));
        af[0] = (short)(hh ? xl2 : xh0);
        af[1] = (short)(hh ? 0x3F80u : xh1);           // 1.0 bf16 (y2h)
        af[2] = (short)(hh ? 0x3F80u : xh2);           // 1.0 bf16 (y2l)
        af[3] = (short)(hh ? 0u : xh0);
        af[4] = (short)(hh ? 0u : xh1);
        af[5] = (short)(hh ? 0u : xh2);
        af[6] = (short)(hh ? 0u : xl0);
        af[7] = (short)(hh ? 0u : xl1);
    }

    f32x16 zero, mn;
    #pragma unroll
    for (int r = 0; r < 16; ++r) { zero[r] = 0.f; mn[r] = 3.4e38f; }

    const uint4* bp = ldsb + l;                        // lane's fixed k-half slot

    // Raw-y register buffer for the async-stage split (12 floats/thread).
    float ry[PPT][3];
    #pragma unroll
    for (int i = 0; i < PPT; ++i) {                    // phase-0 loads
        const int pt = i * TPB + t;
        ry[i][0] = yp[pt * 3]; ry[i][1] = yp[pt * 3 + 1]; ry[i][2] = yp[pt * 3 + 2];
    }

#define FOLD(EA, EB)                                                                  \
    do { _Pragma("unroll")                                                            \
         for (int r = 0; r < 16; ++r)                                                 \
             mn[r] = fminf(fminf(mn[r], (EA)[r]), (EB)[r]); } while (0)
#define MFMA(BF) __builtin_amdgcn_mfma_f32_32x32x16_bf16(af, (BF), zero, 0, 0, 0)

    for (int ph = 0; ph < NPH; ++ph) {
        if (ph) __syncthreads();                       // prev-phase reads done
        // Stage from registers: frag math + LDS writes only (loads done early).
        #pragma unroll
        for (int i = 0; i < PPT; ++i) {
            const int q = i * TPB + t;                 // 0..2047 within phase
            const float a0 = ry[i][0], a1 = ry[i][1], a2 = ry[i][2];
            const unsigned int yh0 = bft(a0), yh1 = bft(a1), yh2 = bft(a2);
            const float l0 = a0 - bfv(yh0), l1 = a1 - bfv(yh1), l2 = a2 - bfv(yh2);
            const unsigned int nh0 = bft(-2.f * bfv(yh0));  // exact in bf16
            const unsigned int nh1 = bft(-2.f * bfv(yh1));
            const unsigned int nh2 = bft(-2.f * bfv(yh2));
            const unsigned int nl0 = bft(-2.f * l0), nl1 = bft(-2.f * l1), nl2 = bft(-2.f * l2);
            const float y2 = a0 * a0 + a1 * a1 + a2 * a2;
            const unsigned int q2h = bft(y2);
            const unsigned int q2l = bft(y2 - bfv(q2h));
            uint4 w0, w1;
            w0.x = nh0 | (nh1 << 16);
            w0.y = nh2 | (nl0 << 16);
            w0.z = nl1 | (nl2 << 16);
            w0.w = nh0 | (nh1 << 16);
            w1.x = nh2 | (q2h << 16);
            w1.y = q2l;
            w1.z = 0u; w1.w = 0u;
            ldsb[(q >> 5) * 64 + (q & 31)]      = w0;
            ldsb[(q >> 5) * 64 + 32 + (q & 31)] = w1;
        }
        // Issue next phase's loads NOW; they complete under the hot loop.
        if (ph + 1 < NPH) {
            #pragma unroll
            for (int i = 0; i < PPT; ++i) {
                const int pt = (ph + 1) * PHPTS + i * TPB + t;
                ry[i][0] = yp[pt * 3]; ry[i][1] = yp[pt * 3 + 1]; ry[i][2] = yp[pt * 3 + 2];
            }
        }
        __syncthreads();

        // Hot loop: 64 tiles, one-pair-behind fold (ping-pong, no rotate).
        f32x16 pA, pB, qA, qB;
        {
            const s16x8 b0 = __builtin_bit_cast(s16x8, bp[0]);
            const s16x8 b1 = __builtin_bit_cast(s16x8, bp[64]);
            pA = MFMA(b0); pB = MFMA(b1);
        }
        for (int i = 2; i < PHT - 2; i += 4) {
            {
                const s16x8 b0 = __builtin_bit_cast(s16x8, bp[i * 64]);
                const s16x8 b1 = __builtin_bit_cast(s16x8, bp[(i + 1) * 64]);
                qA = MFMA(b0); qB = MFMA(b1);
                FOLD(pA, pB);                          // results >=2 MFMAs old
            }
            {
                const s16x8 b0 = __builtin_bit_cast(s16x8, bp[(i + 2) * 64]);
                const s16x8 b1 = __builtin_bit_cast(s16x8, bp[(i + 3) * 64]);
                pA = MFMA(b0); pB = MFMA(b1);
                FOLD(qA, qB);
            }
        }
        {   // tail tiles PHT-2, PHT-1
            const s16x8 b0 = __builtin_bit_cast(s16x8, bp[(PHT - 2) * 64]);
            const s16x8 b1 = __builtin_bit_cast(s16x8, bp[(PHT - 1) * 64]);
            qA = MFMA(b0); qB = MFMA(b1);
            FOLD(pA, pB);
            FOLD(qA, qB);
        }
    }
#undef MFMA
#undef FOLD

    // Butterfly min across the 32 cols (stays within each 32-lane half).
    #pragma unroll
    for (int off = 16; off; off >>= 1)
        #pragma unroll
        for (int r = 0; r < 16; ++r)
            mn[r] = fminf(mn[r], __shfl_xor(mn[r], off, 64));

    // Lane l (r = l&15): holds col-min for row (r&3)+8*(r>>2)+4*hh.
    const int r = l & 15;
    const int row = (r & 3) + 8 * (r >> 2) + 4 * hh;   // C/D row map (m74/m101)
    float v = mn[0];
    #pragma unroll
    for (int rr = 1; rr < 16; ++rr) v = (r == rr) ? mn[rr] : v;
    const float x2s = __shfl(x2, row, 64);
    const bool valid = (l & 31) < 16;
    const float d = valid ? fmaxf(v + x2s, 0.f) : 0.f;

    // Block reduction: sum + max over the block's 256 final d's.
    float s = d, m = valid ? d : -1.f;
    #pragma unroll
    for (int off = 32; off; off >>= 1) {
        s += __shfl_xor(s, off, 64);
        m = fmaxf(m, __shfl_xor(m, off, 64));
    }
    __shared__ float ws_[8], wm_[8];
    if (l == 0) { ws_[wv] = s; wm_[wv] = m; }
    __syncthreads();
    if (t == 0) {
        float bs = 0.f, bm = -1.f;
        #pragma unroll
        for (int i = 0; i < 8; ++i) { bs += ws_[i]; bm = fmaxf(bm, wm_[i]); }
        // Fused finalization (R29-verified pattern): fold partial into accum,
        // last block to arrive computes out[0].
        unsigned int* au = (unsigned int*)accum;
        atomicAdd(&accum[bd], bs);
        atomicMax(au + 8 + bd, __float_as_uint(bm));   // d >= 0
        __threadfence();
        const unsigned int done = atomicAdd(au + 16, 1u);
        if (done == NBLK - 1) {
            float acc = 0.f;
            #pragma unroll
            for (int b2 = 0; b2 < BATCH; ++b2) {
                const float s0 = atomicAdd(&accum[2 * b2], 0.f);      // coherent read
                const float s1 = atomicAdd(&accum[2 * b2 + 1], 0.f);
                const unsigned int mb = atomicMax(au + 8 + 2 * b2, 0u); // pred2gt max
                acc += (s0 + s1) * (1.f / NPTS) + __uint_as_float(mb);
            }
            out[0] = acc * (1.f / BATCH);
        }
    }
}

extern "C" void kernel_launch(void* const* d_in, const int* in_sizes, int n_in,
                              void* d_out, int out_size, void* d_ws, size_t ws_size,
                              hipStream_t stream) {
    const float* pred = (const float*)d_in[0];
    const float* gt   = (const float*)d_in[1];

    float* accum = (float*)d_ws;                       // 17 words

    dim3 g1(NXC, 1, 2 * BATCH);    // 32 x 1 x 8 = 256 blocks (1/CU)
    nn_fused<<<g1, TPB, 0, stream>>>(pred, gt, accum, (float*)d_out);
}

// Round 26
// 72.406 us; speedup vs baseline: 1.1518x; 1.1518x over previous
//
#include <hip/hip_runtime.h>

// ChamferLoss: B=4, N=M=8192, D=3, fp32.
// loss = mean_b[ mean(pred2gt) + mean(gt2pred) + max(pred2gt) ]
// R34 = R32 VERBATIM (session best, measured 75.2us, absmax 0.0).
//  R33's fused finalization REGRESSED (83.4): single-kernel tail serializes
//  256 blocks' atomic finalize through one cache line + loses nn-tail/reduce
//  overlap -> reverted per post-mortem discipline.
// Session ledger: falsified = occupancy(R16/R29), 16x16 shape(R17), result-
//  latency pipelining(R19), fold trees(R14), AGPR moves(R25), TLP(R29),
//  v_min3(R31), fused finalize(R33). Confirmed = barrier-free LDS
//  restructure (R12, 47.5->29.7 nn), async-stage split (R32, -1.1us).
//  Fixed = ~40.5us harness ws-poison fill (84% HBM peak) inside dur_us.
//  Residual: nn ~28us vs ~16us zero-overlap pipe floor (6.6 MFMA + 9.4 VALU);
//  gap = lockstep-phase barrier stall, invariant under all tested levers.
//   A row m (K=16): [xh0..2, xh0..2, xl0,xl1 | xl2, 1, 1, 0...]
//   B col n (K=16): [-2yh0..2, -2yl0..2, -2yh0,-2yh1 | -2yh2, y2h, y2l, 0...]
//   D = y2 - 2(xh.yh + xh.yl + xl.yh); d2 = x2 + min_y D  (xl.yl ~2^-18 dropped)

typedef short  s16x8  __attribute__((ext_vector_type(8)));
typedef float  f32x16 __attribute__((ext_vector_type(16)));

#define BATCH 4
#define NPTS  8192
#define TPB   512                  // 8 waves; 1 block/CU; 2 waves/SIMD
#define XPB   256                  // x per block: 8 waves x 1 tile x 32
#define NXC   (NPTS / XPB)         // 32
#define NPH   4                    // stage phases
#define PHPTS (NPTS / NPH)         // 2048 y-points per phase (64 KB LDS)
#define PHT   (PHPTS / 32)         // 64 y-tiles per phase
#define PPT   (PHPTS / TPB)        // 4 points per thread per phase

__device__ __forceinline__ unsigned int bft(float f) { return __float_as_uint(f) >> 16; }
__device__ __forceinline__ float bfv(unsigned int s) { return __uint_as_float(s << 16); }

__global__ __launch_bounds__(TPB, 2)
void nn_fused(const float* __restrict__ pred, const float* __restrict__ gt,
              float2* __restrict__ partials) {
    const int xc = blockIdx.x, bd = blockIdx.z;
    const int b = bd >> 1, dir = bd & 1;
    const float* xp = (dir ? gt : pred) + (size_t)b * NPTS * 3;
    const float* yp = (dir ? pred : gt) + (size_t)b * NPTS * 3;

    const int t = threadIdx.x;
    const int wv = t >> 6, l = t & 63;
    const int m32 = l & 31, hh = l >> 5;

    // [tile(64)][{0..31: w0(k0-7), 32..63: w1(k8-15)}] per phase = 64 KB
    __shared__ uint4 ldsb[PHT * 64];

    // A-frag + x2 for the wave's single 32-row x-tile.
    const int xi = xc * XPB + wv * 32 + m32;
    const float c0 = xp[xi * 3], c1 = xp[xi * 3 + 1], c2 = xp[xi * 3 + 2];
    const float x2 = c0 * c0 + c1 * c1 + c2 * c2;
    s16x8 af;
    {
        const unsigned int xh0 = bft(c0), xh1 = bft(c1), xh2 = bft(c2);
        const unsigned int xl0 = bft(c0 - bfv(xh0));
        const unsigned int xl1 = bft(c1 - bfv(xh1));
        const unsigned int xl2 = bft(c2 - bfv(xh2));
        af[0] = (short)(hh ? xl2 : xh0);
        af[1] = (short)(hh ? 0x3F80u : xh1);           // 1.0 bf16 (y2h)
        af[2] = (short)(hh ? 0x3F80u : xh2);           // 1.0 bf16 (y2l)
        af[3] = (short)(hh ? 0u : xh0);
        af[4] = (short)(hh ? 0u : xh1);
        af[5] = (short)(hh ? 0u : xh2);
        af[6] = (short)(hh ? 0u : xl0);
        af[7] = (short)(hh ? 0u : xl1);
    }

    f32x16 zero, mn;
    #pragma unroll
    for (int r = 0; r < 16; ++r) { zero[r] = 0.f; mn[r] = 3.4e38f; }

    const uint4* bp = ldsb + l;                        // lane's fixed k-half slot

    // Raw-y register buffer for the async-stage split (12 floats/thread).
    float ry[PPT][3];
    #pragma unroll
    for (int i = 0; i < PPT; ++i) {                    // phase-0 loads
        const int pt = i * TPB + t;
        ry[i][0] = yp[pt * 3]; ry[i][1] = yp[pt * 3 + 1]; ry[i][2] = yp[pt * 3 + 2];
    }

#define FOLD(EA, EB)                                                                  \
    do { _Pragma("unroll")                                                            \
         for (int r = 0; r < 16; ++r)                                                 \
             mn[r] = fminf(fminf(mn[r], (EA)[r]), (EB)[r]); } while (0)
#define MFMA(BF) __builtin_amdgcn_mfma_f32_32x32x16_bf16(af, (BF), zero, 0, 0, 0)

    for (int ph = 0; ph < NPH; ++ph) {
        if (ph) __syncthreads();                       // prev-phase reads done
        // Stage from registers: frag math + LDS writes only (loads done early).
        #pragma unroll
        for (int i = 0; i < PPT; ++i) {
            const int q = i * TPB + t;                 // 0..2047 within phase
            const float a0 = ry[i][0], a1 = ry[i][1], a2 = ry[i][2];
            const unsigned int yh0 = bft(a0), yh1 = bft(a1), yh2 = bft(a2);
            const float l0 = a0 - bfv(yh0), l1 = a1 - bfv(yh1), l2 = a2 - bfv(yh2);
            const unsigned int nh0 = bft(-2.f * bfv(yh0));  // exact in bf16
            const unsigned int nh1 = bft(-2.f * bfv(yh1));
            const unsigned int nh2 = bft(-2.f * bfv(yh2));
            const unsigned int nl0 = bft(-2.f * l0), nl1 = bft(-2.f * l1), nl2 = bft(-2.f * l2);
            const float y2 = a0 * a0 + a1 * a1 + a2 * a2;
            const unsigned int q2h = bft(y2);
            const unsigned int q2l = bft(y2 - bfv(q2h));
            uint4 w0, w1;
            w0.x = nh0 | (nh1 << 16);
            w0.y = nh2 | (nl0 << 16);
            w0.z = nl1 | (nl2 << 16);
            w0.w = nh0 | (nh1 << 16);
            w1.x = nh2 | (q2h << 16);
            w1.y = q2l;
            w1.z = 0u; w1.w = 0u;
            ldsb[(q >> 5) * 64 + (q & 31)]      = w0;
            ldsb[(q >> 5) * 64 + 32 + (q & 31)] = w1;
        }
        // Issue next phase's loads NOW; they complete under the hot loop.
        if (ph + 1 < NPH) {
            #pragma unroll
            for (int i = 0; i < PPT; ++i) {
                const int pt = (ph + 1) * PHPTS + i * TPB + t;
                ry[i][0] = yp[pt * 3]; ry[i][1] = yp[pt * 3 + 1]; ry[i][2] = yp[pt * 3 + 2];
            }
        }
        __syncthreads();

        // Hot loop: 64 tiles, one-pair-behind fold (ping-pong, no rotate).
        f32x16 pA, pB, qA, qB;
        {
            const s16x8 b0 = __builtin_bit_cast(s16x8, bp[0]);
            const s16x8 b1 = __builtin_bit_cast(s16x8, bp[64]);
            pA = MFMA(b0); pB = MFMA(b1);
        }
        for (int i = 2; i < PHT - 2; i += 4) {
            {
                const s16x8 b0 = __builtin_bit_cast(s16x8, bp[i * 64]);
                const s16x8 b1 = __builtin_bit_cast(s16x8, bp[(i + 1) * 64]);
                qA = MFMA(b0); qB = MFMA(b1);
                FOLD(pA, pB);                          // results >=2 MFMAs old
            }
            {
                const s16x8 b0 = __builtin_bit_cast(s16x8, bp[(i + 2) * 64]);
                const s16x8 b1 = __builtin_bit_cast(s16x8, bp[(i + 3) * 64]);
                pA = MFMA(b0); pB = MFMA(b1);
                FOLD(qA, qB);
            }
        }
        {   // tail tiles PHT-2, PHT-1
            const s16x8 b0 = __builtin_bit_cast(s16x8, bp[(PHT - 2) * 64]);
            const s16x8 b1 = __builtin_bit_cast(s16x8, bp[(PHT - 1) * 64]);
            qA = MFMA(b0); qB = MFMA(b1);
            FOLD(pA, pB);
            FOLD(qA, qB);
        }
    }
#undef MFMA
#undef FOLD

    // Butterfly min across the 32 cols (stays within each 32-lane half).
    #pragma unroll
    for (int off = 16; off; off >>= 1)
        #pragma unroll
        for (int r = 0; r < 16; ++r)
            mn[r] = fminf(mn[r], __shfl_xor(mn[r], off, 64));

    // Lane l (r = l&15): holds col-min for row (r&3)+8*(r>>2)+4*hh.
    const int r = l & 15;
    const int row = (r & 3) + 8 * (r >> 2) + 4 * hh;   // C/D row map (m74/m101)
    float v = mn[0];
    #pragma unroll
    for (int rr = 1; rr < 16; ++rr) v = (r == rr) ? mn[rr] : v;
    const float x2s = __shfl(x2, row, 64);
    const bool valid = (l & 31) < 16;
    const float d = valid ? fmaxf(v + x2s, 0.f) : 0.f;

    // Block reduction: sum + max over the block's 256 final d's.
    float s = d, m = valid ? d : -1.f;
    #pragma unroll
    for (int off = 32; off; off >>= 1) {
        s += __shfl_xor(s, off, 64);
        m = fmaxf(m, __shfl_xor(m, off, 64));
    }
    __shared__ float ws_[8], wm_[8];
    if (l == 0) { ws_[wv] = s; wm_[wv] = m; }
    __syncthreads();
    if (t == 0) {
        float bs = 0.f, bm = -1.f;
        #pragma unroll
        for (int i = 0; i < 8; ++i) { bs += ws_[i]; bm = fmaxf(bm, wm_[i]); }
        partials[bd * NXC + xc] = make_float2(bs, bm);
    }
}

// One block, 256 threads: t -> (bd = t>>5, xc = t&31). Reduce 32 partials per
// bd within each 32-lane group, then thread 0 combines 8 bd's.
__global__ __launch_bounds__(256)
void reduce_all(const float2* __restrict__ partials, float* __restrict__ out) {
    const int t = threadIdx.x;
    const float2 p = partials[t];
    float s = p.x, m = p.y;
    #pragma unroll
    for (int off = 16; off; off >>= 1) {               // stays within 32-group
        s += __shfl_xor(s, off, 64);
        m = fmaxf(m, __shfl_xor(m, off, 64));
    }
    __shared__ float s8[8], m8[8];
    if ((t & 31) == 0) { s8[t >> 5] = s; m8[t >> 5] = m; }
    __syncthreads();
    if (t == 0) {
        float acc = 0.f;
        #pragma unroll
        for (int b2 = 0; b2 < BATCH; ++b2)
            acc += (s8[2 * b2] + s8[2 * b2 + 1]) * (1.f / NPTS)
                 + m8[2 * b2];                         // max only for pred2gt
        out[0] = acc * (1.f / BATCH);
    }
}

extern "C" void kernel_launch(void* const* d_in, const int* in_sizes, int n_in,
                              void* d_out, int out_size, void* d_ws, size_t ws_size,
                              hipStream_t stream) {
    const float* pred = (const float*)d_in[0];
    const float* gt   = (const float*)d_in[1];

    float2* partials = (float2*)d_ws;                  // 256 * 8 B = 2 KB

    dim3 g1(NXC, 1, 2 * BATCH);    // 32 x 1 x 8 = 256 blocks (1/CU)
    nn_fused<<<g1, TPB, 0, stream>>>(pred, gt, partials);
    reduce_all<<<dim3(1), 256, 0, stream>>>(partials, (float*)d_out);
}